// Round 10
// baseline (1344.400 us; speedup 1.0000x reference)
//
#include <hip/hip_runtime.h>

#define N_B 256
#define T_SEQ 32

typedef short short8 __attribute__((ext_vector_type(8)));
typedef float floatx4 __attribute__((ext_vector_type(4)));
typedef unsigned short ushort_t;

// ---- scratch as device globals (no dependence on ws_size) ------------------
__device__ __align__(16) ushort_t g_W3 [(size_t)4096 * 3072];      // 24 MB [j][k]=[Wh^T|Wx^T|Wattn^T]
__device__ __align__(16) ushort_t g_xb [(size_t)8192 * 1024];      // 16 MB bf16 x, row = t*256+n
__device__ __align__(16) ushort_t g_Ab [(size_t)N_B * 16384];      // 8 MB bf16 A [n][h][l]
__device__ __align__(16) ushort_t g_Hs[T_SEQ + 1][N_B * 1024];     // 17 MB h ring: FRESH buf/step
__device__ __align__(16) ushort_t g_attn[T_SEQ][N_B * 1024];       // 16 MB attn ring: FRESH buf/step
__device__ __align__(16) float    g_c [N_B * 1024];                // fp32 cell state (init only)
__device__ __align__(16) float    g_lg[T_SEQ][8][N_B][16];         // 4 MB logit ring: FRESH buf/step
__device__ __align__(128) unsigned int g_sub[16 * 32];             // barrier sub-counters (padded)
__device__ unsigned int g_master;                                  // barrier master counter

__device__ __forceinline__ float bf2f(ushort_t u){
    union { unsigned int i; float f; } v; v.i = ((unsigned int)u) << 16; return v.f;
}
__device__ __forceinline__ ushort_t f2bf(float f){
    union { unsigned int i; float f; } v; v.f = f;
    unsigned int i = v.i;
    unsigned int r = (i + 0x7FFFu + ((i >> 16) & 1u)) >> 16;
    return (ushort_t)r;
}
__device__ __forceinline__ float fast_tanh(float x){
    float e = __expf(2.f * x);
    return 1.f - 2.f / (e + 1.f);
}
// async global->LDS, 16B per lane. Plain cached everywhere: all cross-block
// state (H, attn, logits) rotates through FRESH addresses each step, so no
// cache can hold a stale copy; release fence (wbl2) pushes writes to the
// coherence point before readers' first touch.
__device__ __forceinline__ void gload16(const ushort_t* g, ushort_t* l) {
    __builtin_amdgcn_global_load_lds((const __attribute__((address_space(1))) void*)g,
                                     (__attribute__((address_space(3))) void*)l, 16, 0, 0);
}
__device__ __forceinline__ void unp8(uint4 u, float* f) {
    const ushort_t* s = (const ushort_t*)&u;
    #pragma unroll
    for (int i = 0; i < 8; ++i) f[i] = bf2f(s[i]);
}

// Grid barrier, cache-preserving: per-wave vmcnt drain, leader-only RELEASE
// fence (buffer_wbl2 writeback -- no invalidate ever executed), two-level
// relaxed-atomic arrive (16 padded subs -> master), RELAXED polling.
__device__ __forceinline__ void grid_bar(int b, unsigned nbar) {
    asm volatile("s_waitcnt vmcnt(0)" ::: "memory");   // my stores/atomics issued
    __syncthreads();
    if (threadIdx.x == 0) {
        __scoped_atomic_thread_fence(__ATOMIC_RELEASE, __MEMORY_SCOPE_DEVICE);  // wbl2
        __hip_atomic_fetch_add(&g_sub[(b & 15) * 32], 1u,
                               __ATOMIC_RELAXED, __HIP_MEMORY_SCOPE_AGENT);
        if (b < 16) {
            while (__hip_atomic_load(&g_sub[b * 32], __ATOMIC_RELAXED,
                                     __HIP_MEMORY_SCOPE_AGENT) < 32u * nbar)
                __builtin_amdgcn_s_sleep(2);
            __hip_atomic_fetch_add(&g_master, 1u,
                                   __ATOMIC_RELAXED, __HIP_MEMORY_SCOPE_AGENT);
        }
        while (__hip_atomic_load(&g_master, __ATOMIC_RELAXED,
                                 __HIP_MEMORY_SCOPE_AGENT) < 16u * nbar)
            __builtin_amdgcn_s_sleep(2);
    }
    __syncthreads();
}

// ---------------------------------------------------------------------------
// x (fp32 [n][t][d]) -> g_xb (bf16, row t*256+n). grid 8192 x 128.
// ---------------------------------------------------------------------------
__global__ __launch_bounds__(128) void cvt_x(const float* __restrict__ x)
{
    int b = blockIdx.x;                 // in-row = n*32 + t
    int n = b >> 5, tt = b & 31;
    int tid = threadIdx.x;
    const float* src = x + (size_t)b * 1024 + tid * 8;
    float4 a = *(const float4*)src;
    float4 c = *(const float4*)(src + 4);
    ushort_t r[8];
    r[0]=f2bf(a.x); r[1]=f2bf(a.y); r[2]=f2bf(a.z); r[3]=f2bf(a.w);
    r[4]=f2bf(c.x); r[5]=f2bf(c.y); r[6]=f2bf(c.z); r[7]=f2bf(c.w);
    *(uint4*)(g_xb + (size_t)(tt * 256 + n) * 1024 + tid * 8) = *(const uint4*)r;
}

// ---------------------------------------------------------------------------
// A fp32 [n][h][l] -> g_Ab bf16 (same layout). grid 256 x 256.
// ---------------------------------------------------------------------------
__global__ __launch_bounds__(256) void cvt_a(const float* __restrict__ A)
{
    int n = blockIdx.x, tid = threadIdx.x;
    int h0 = tid * 4;
    const float* ap = A + (size_t)n * 16384;
    #pragma unroll
    for (int i = 0; i < 4; ++i) {
        const float* row = ap + (size_t)(h0 + i) * 16;
        ushort_t tmp[16];
        #pragma unroll
        for (int l = 0; l < 16; ++l) tmp[l] = f2bf(row[l]);
        ushort_t* dst = g_Ab + (size_t)n * 16384 + (size_t)(h0 + i) * 16;
        *(uint4*)dst       = *(const uint4*)&tmp[0];
        *(uint4*)(dst + 8) = *(const uint4*)&tmp[8];
    }
}

// ---------------------------------------------------------------------------
// Prepack [Wh^T | Wx^T | Wattn^T] -> g_W3 [j][k3] (4096 x 3072).
// grid (48,64) x 256.
// ---------------------------------------------------------------------------
__global__ __launch_bounds__(256) void prepack_w3(
    const float* __restrict__ Wh, const float* __restrict__ Wx,
    const float* __restrict__ Wattn)
{
    __shared__ ushort_t tile[64][66];
    int k0 = blockIdx.x * 64, j0 = blockIdx.y * 64;
    const float* src = (k0 < 1024) ? Wh : (k0 < 2048) ? Wx : Wattn;
    int krel = k0 & 1023;
    int c = threadIdx.x & 63, r4 = threadIdx.x >> 6;
    for (int rr = 0; rr < 64; rr += 4) {
        int r = rr + r4;
        tile[r][c] = f2bf(src[(size_t)(krel + r) * 4096 + j0 + c]);
    }
    __syncthreads();
    for (int rr = 0; rr < 64; rr += 4) {
        int j = rr + r4;
        g_W3[(size_t)(j0 + j) * 3072 + k0 + c] = tile[c][j];
    }
}

// ---------------------------------------------------------------------------
// Zero ALL logit ring buffers + barrier counters (per-replay reset).
// grid 4096 x 256 covers 32*8*256*16 = 1048576 floats.
// ---------------------------------------------------------------------------
__global__ __launch_bounds__(256) void zero_lg()
{
    int i = blockIdx.x * 256 + threadIdx.x;
    ((float*)g_lg)[i] = 0.f;
    if (i < 512) g_sub[i] = 0u;
    if (i == 0) g_master = 0u;
}

// ---------------------------------------------------------------------------
// Init: h0 = c0 = mean over 16 spatial of A; accumulate t=0 logits into
// g_lg[0][0] (fp32 atomics; slices 1..7 stay zero). grid 1024 x 256.
// ---------------------------------------------------------------------------
__global__ __launch_bounds__(256) void init_hc(const float* __restrict__ A)
{
    __shared__ float l1[16 * 257];     // [l][t] padded
    __shared__ float l2[16 * 16];      // [l][seg]
    int b = blockIdx.x;
    int n = b >> 2;
    int tid = threadIdx.x;
    int gid = b * 256 + tid;           // (n, h) with h = (b&3)*256+tid
    const float* ap = A + ((size_t)gid << 4);
    float a[16];
    *(float4*)(a)      = *(const float4*)(ap);
    *(float4*)(a + 4)  = *(const float4*)(ap + 4);
    *(float4*)(a + 8)  = *(const float4*)(ap + 8);
    *(float4*)(a + 12) = *(const float4*)(ap + 12);
    float s = 0.f;
    #pragma unroll
    for (int l = 0; l < 16; ++l) s += a[l];
    s *= (1.0f / 16.0f);
    g_Hs[0][gid] = f2bf(s);
    g_c[gid] = s;
    #pragma unroll
    for (int l = 0; l < 16; ++l) l1[l * 257 + tid] = s * a[l];
    __syncthreads();
    {
        int l = tid >> 4, seg = tid & 15;
        float s2 = 0.f;
        #pragma unroll
        for (int i = 0; i < 16; ++i) s2 += l1[l * 257 + seg * 16 + i];
        l2[l * 16 + seg] = s2;
    }
    __syncthreads();
    if (tid < 16) {
        float lg = 0.f;
        #pragma unroll
        for (int i = 0; i < 16; ++i) lg += l2[tid * 16 + i];
        atomicAdd(&g_lg[0][0][n][tid], lg);
    }
}

// ---------------------------------------------------------------------------
// Persistent step loop v4b: attention as third K-segment (K=3072, 24 iters).
// FIX vs round 9: attn-slice computation now covers ALL 32 rows of the
// block's n-tile (e-loop over 512 (nl,hl) pairs; round 9 only wrote 16 rows,
// leaving half of g_attn uninitialized -> absmax 1.0).
// ---------------------------------------------------------------------------
__global__ __launch_bounds__(256, 2) void step_loop(float* __restrict__ out,
                                                    const float* __restrict__ bias)
{
    __shared__ __align__(16) char smem[51200];
    ushort_t* lA0 = (ushort_t*)smem;                 // 32x128 bf16 (8 KB)
    ushort_t* lA1 = (ushort_t*)(smem + 8192);
    ushort_t* lB0 = (ushort_t*)(smem + 16384);       // 64x128 bf16 (16 KB)
    ushort_t* lB1 = (ushort_t*)(smem + 32768);
    float*    lP  = (float*)smem;                    // [4][32*68] epilogue alias
    float*    lq  = (float*)smem;                    // [512*17] logit alias
    float*    lw  = (float*)(smem + 49152);          // [32][16] softmax weights

    int b = blockIdx.x;
    int xcd = b & 7, r = b >> 3;
    int jt = xcd * 8 + (r & 7), nt = r >> 3;
    int n0 = nt * 32, hh0 = jt * 16;
    int tid = threadIdx.x, lane = tid & 63, wv = tid >> 6;
    int lm = lane & 15, quad = lane >> 4;
    int srow = lane >> 4, sseg = lane & 15;

    const ushort_t* gB0 = g_W3 + (size_t)(wv * 1024 + hh0 + srow) * 3072;

    // persistent block-private cell state: 2 elements per thread
    float creg[2];
    {
        int nlA = tid >> 4, hlA = tid & 15;
        creg[0] = g_c[(n0 + nlA) * 1024 + hh0 + hlA];
        creg[1] = g_c[(n0 + 16 + nlA) * 1024 + hh0 + hlA];
    }

    unsigned nbar = 0;
    for (int t = 0; t < T_SEQ; ++t) {
        if (t) { ++nbar; grid_bar(b, nbar); }

        const ushort_t* hbase = g_Hs[t] + (size_t)(n0 + wv * 8 + srow) * 1024;
        const ushort_t* xbase = g_xb + ((size_t)t * 256 + n0 + wv * 8 + srow) * 1024;
        const ushort_t* abase = g_attn[t] + (size_t)(n0 + wv * 8 + srow) * 1024;
        ushort_t*       Hout  = g_Hs[t + 1];

        // ---- issue tile-0 staging early (h + W3; barrier-#2-independent) ----
        #pragma unroll
        for (int i = 0; i < 2; ++i) {
            int rlow = (wv * 8 + i * 4 + srow) & 15;
            gload16(hbase + (size_t)i * 4 * 1024 + (sseg ^ rlow) * 8,
                    lA0 + (wv * 8 + i * 4) * 128);
        }
        #pragma unroll
        for (int i = 0; i < 4; ++i) {
            int rlow = i * 4 + srow;
            gload16(gB0 + (size_t)i * 4 * 3072 + (sseg ^ rlow) * 8,
                    lB0 + (wv * 16 + i * 4) * 128);
        }

        // ---- softmax weights from fresh logit buffer ----
        #pragma unroll
        for (int e = 0; e < 2; ++e) {
            int idx = tid + e * 256;
            int nl = idx >> 4, l = idx & 15;
            float v = 0.f;
            #pragma unroll
            for (int s = 0; s < 8; ++s) v += g_lg[t][s][n0 + nl][l];
            v *= 0.03125f;                                   // 1/sqrt(H)
            float mx = v;
            mx = fmaxf(mx, __shfl_xor(mx, 1));
            mx = fmaxf(mx, __shfl_xor(mx, 2));
            mx = fmaxf(mx, __shfl_xor(mx, 4));
            mx = fmaxf(mx, __shfl_xor(mx, 8));
            float ex = __expf(v - mx);
            float sm = ex;
            sm += __shfl_xor(sm, 1);
            sm += __shfl_xor(sm, 2);
            sm += __shfl_xor(sm, 4);
            sm += __shfl_xor(sm, 8);
            lw[nl * 16 + l] = ex / sm;
        }
        __syncthreads();                   // lw visible to all threads

        // ---- this block's attn slice: ALL 32 rows x 16 cols (disjoint) ----
        #pragma unroll
        for (int e = 0; e < 2; ++e) {
            int idx = tid + e * 256;
            int nl = idx >> 4, hl = idx & 15;
            const ushort_t* ar = g_Ab + (size_t)(n0 + nl) * 16384 + (size_t)(hh0 + hl) * 16;
            float av[16];
            unp8(*(const uint4*)ar, av);
            unp8(*(const uint4*)(ar + 8), av + 8);
            float a = 0.f;
            #pragma unroll
            for (int l = 0; l < 16; ++l) a += lw[nl * 16 + l] * av[l];
            g_attn[t][(size_t)(n0 + nl) * 1024 + hh0 + hl] = f2bf(a);
        }
        ++nbar; grid_bar(b, nbar);         // attn published (also drains staging)

        // ---- K-loop: 24 double-buffered iters over [h|x|attn], vmcnt(6) ----
        floatx4 acc[2][4] = {};
        int segk = wv * 4 + quad;
        for (int it = 0; it < 24; ++it) {
            ushort_t* cA = (it & 1) ? lA1 : lA0;
            ushort_t* cB = (it & 1) ? lB1 : lB0;
            ushort_t* nA = (it & 1) ? lA0 : lA1;
            ushort_t* nB = (it & 1) ? lB0 : lB1;
            if (it < 23) {
                int kk = (it + 1) * 128;
                const ushort_t* aSrc = (kk < 1024) ? (hbase + kk)
                                     : (kk < 2048) ? (xbase + (kk - 1024))
                                                   : (abase + (kk - 2048));
                #pragma unroll
                for (int i = 0; i < 2; ++i) {
                    int rlow = (wv * 8 + i * 4 + srow) & 15;
                    gload16(aSrc + (size_t)i * 4 * 1024 + (sseg ^ rlow) * 8,
                            nA + (wv * 8 + i * 4) * 128);
                }
                #pragma unroll
                for (int i = 0; i < 4; ++i) {
                    int rlow = i * 4 + srow;
                    gload16(gB0 + (size_t)i * 4 * 3072 + kk + (sseg ^ rlow) * 8,
                            nB + (wv * 16 + i * 4) * 128);
                }
                asm volatile("s_waitcnt vmcnt(6)" ::: "memory");
            } else {
                asm volatile("s_waitcnt vmcnt(0)" ::: "memory");
            }
            __builtin_amdgcn_s_barrier();
            short8 af[2], bq[4];
            #pragma unroll
            for (int i = 0; i < 2; ++i)
                af[i] = *(const short8*)(cA + (i * 16 + lm) * 128 + ((segk ^ lm) * 8));
            #pragma unroll
            for (int j = 0; j < 4; ++j)
                bq[j] = *(const short8*)(cB + (j * 16 + lm) * 128 + ((segk ^ lm) * 8));
            #pragma unroll
            for (int i = 0; i < 2; ++i)
                #pragma unroll
                for (int j = 0; j < 4; ++j)
                    acc[i][j] = __builtin_amdgcn_mfma_f32_16x16x32_bf16(af[i], bq[j], acc[i][j], 0, 0, 0);
            asm volatile("s_waitcnt lgkmcnt(0)" ::: "memory");
            __builtin_amdgcn_s_barrier();
        }

        // ---- wave-private partial store ----
        float* my = lP + wv * (32 * 68);
        #pragma unroll
        for (int i = 0; i < 2; ++i)
            #pragma unroll
            for (int j = 0; j < 4; ++j)
                #pragma unroll
                for (int q = 0; q < 4; ++q)
                    my[(i * 16 + quad * 4 + q) * 68 + j * 16 + lm] = acc[i][j][q];
        __syncthreads();

        // ---- LSTM pointwise: 4 wave-partials + bias (attn already in GEMM) ----
        float hsave[2];
        #pragma unroll
        for (int e = 0; e < 2; ++e) {
            int idx = tid + e * 256;           // (nl, hl)
            int nl = idx >> 4, hl = idx & 15;
            int base = nl * 68 + hl;
            float s0 = lP[base]      + lP[2176 + base]      + lP[4352 + base]      + lP[6528 + base];
            float s1 = lP[base + 16] + lP[2176 + base + 16] + lP[4352 + base + 16] + lP[6528 + base + 16];
            float s2 = lP[base + 32] + lP[2176 + base + 32] + lP[4352 + base + 32] + lP[6528 + base + 32];
            float s3 = lP[base + 48] + lP[2176 + base + 48] + lP[4352 + base + 48] + lP[6528 + base + 48];
            int hg = hh0 + hl;
            float ai  = s0 + bias[hg];
            float afv = s1 + bias[1024 + hg];
            float ao  = s2 + bias[2048 + hg];
            float ag  = s3 + bias[3072 + hg];
            float iv = 1.f / (1.f + __expf(-ai));
            float fv = 1.f / (1.f + __expf(-afv));
            float ov = 1.f / (1.f + __expf(-ao));
            float gv = fast_tanh(ag);
            float cnew = fv * creg[e] + iv * gv;
            float hnew = ov * fast_tanh(cnew);
            creg[e] = cnew;
            int ng = n0 + nl;
            Hout[ng * 1024 + hg] = f2bf(hnew);
            out[(size_t)ng * (T_SEQ * 1024) + (size_t)t * 1024 + hg] = hnew;
            hsave[e] = hnew;
        }

        // ---- logit partial for t+1 (8-sliced atomics into fresh buffer) ----
        if (t < T_SEQ - 1) {
            __syncthreads();               // lP reads done before lq overwrite
            #pragma unroll
            for (int e = 0; e < 2; ++e) {
                int idx = tid + e * 256;
                int nl = idx >> 4, hl = idx & 15;
                const ushort_t* ar = g_Ab + (size_t)(n0 + nl) * 16384 + (size_t)(hh0 + hl) * 16;
                float av[16];
                unp8(*(const uint4*)ar, av);
                unp8(*(const uint4*)(ar + 8), av + 8);
                float hv = hsave[e];
                #pragma unroll
                for (int l = 0; l < 16; ++l)
                    lq[(nl * 16 + l) * 17 + hl] = hv * av[l];
            }
            __syncthreads();
            #pragma unroll
            for (int e = 0; e < 2; ++e) {
                int idx = tid + e * 256;
                int nl = idx >> 4, l = idx & 15;
                float s = 0.f;
                #pragma unroll
                for (int k = 0; k < 16; ++k) s += lq[(nl * 16 + l) * 17 + k];
                atomicAdd(&g_lg[t + 1][jt & 7][n0 + nl][l], s);
            }
        }
    }
}

// ---------------------------------------------------------------------------
extern "C" void kernel_launch(void* const* d_in, const int* in_sizes, int n_in,
                              void* d_out, int out_size, void* d_ws, size_t ws_size,
                              hipStream_t stream) {
    const float* x     = (const float*)d_in[0];
    const float* A     = (const float*)d_in[1];
    const float* Wx    = (const float*)d_in[2];
    const float* Wh    = (const float*)d_in[3];
    const float* Wattn = (const float*)d_in[4];
    const float* bias  = (const float*)d_in[5];
    float* out = (float*)d_out;

    cvt_x<<<8192, 128, 0, stream>>>(x);
    cvt_a<<<256, 256, 0, stream>>>(A);
    prepack_w3<<<dim3(48, 64), 256, 0, stream>>>(Wh, Wx, Wattn);
    zero_lg<<<4096, 256, 0, stream>>>();
    init_hc<<<1024, 256, 0, stream>>>(A);
    step_loop<<<512, 256, 0, stream>>>(out, bias);
}

// Round 11
// 963.345 us; speedup vs baseline: 1.3956x; 1.3956x over previous
//
#include <hip/hip_runtime.h>

#define N_B 256
#define T_SEQ 32

typedef short short8 __attribute__((ext_vector_type(8)));
typedef float floatx4 __attribute__((ext_vector_type(4)));
typedef unsigned short ushort_t;

// ---- scratch as device globals (no dependence on ws_size) ------------------
__device__ __align__(16) ushort_t g_W3 [(size_t)4096 * 3072];      // 24 MB [j][k]=[Wh^T|Wx^T|Wattn^T]
__device__ __align__(16) ushort_t g_xb [(size_t)8192 * 1024];      // 16 MB bf16 x, row = t*256+n
__device__ __align__(16) ushort_t g_Ab [(size_t)N_B * 16384];      // 8 MB bf16 A [n][h][l]
__device__ __align__(16) ushort_t g_Hc[2][N_B * 1024];             // h bf16 ping-pong
__device__ __align__(16) ushort_t g_attn[N_B * 1024];              // 0.5 MB bf16 attn (per-step)
__device__ __align__(16) float    g_c [N_B * 1024];                // fp32 cell state

__device__ __forceinline__ float bf2f(ushort_t u){
    union { unsigned int i; float f; } v; v.i = ((unsigned int)u) << 16; return v.f;
}
__device__ __forceinline__ ushort_t f2bf(float f){
    union { unsigned int i; float f; } v; v.f = f;
    unsigned int i = v.i;
    unsigned int r = (i + 0x7FFFu + ((i >> 16) & 1u)) >> 16;
    return (ushort_t)r;
}
__device__ __forceinline__ float fast_tanh(float x){
    float e = __expf(2.f * x);
    return 1.f - 2.f / (e + 1.f);
}
// async global->LDS, 16B per lane; launch boundaries provide all cross-kernel
// coherence (no barriers, no fences, no coherent-bypass loads).
__device__ __forceinline__ void gload16(const ushort_t* g, ushort_t* l) {
    __builtin_amdgcn_global_load_lds((const __attribute__((address_space(1))) void*)g,
                                     (__attribute__((address_space(3))) void*)l, 16, 0, 0);
}
__device__ __forceinline__ void unp8(uint4 u, float* f) {
    const ushort_t* s = (const ushort_t*)&u;
    #pragma unroll
    for (int i = 0; i < 8; ++i) f[i] = bf2f(s[i]);
}

// ---------------------------------------------------------------------------
// x (fp32 [n][t][d]) -> g_xb (bf16, row t*256+n). grid 8192 x 128.
// ---------------------------------------------------------------------------
__global__ __launch_bounds__(128) void cvt_x(const float* __restrict__ x)
{
    int b = blockIdx.x;                 // in-row = n*32 + t
    int n = b >> 5, tt = b & 31;
    int tid = threadIdx.x;
    const float* src = x + (size_t)b * 1024 + tid * 8;
    float4 a = *(const float4*)src;
    float4 c = *(const float4*)(src + 4);
    ushort_t r[8];
    r[0]=f2bf(a.x); r[1]=f2bf(a.y); r[2]=f2bf(a.z); r[3]=f2bf(a.w);
    r[4]=f2bf(c.x); r[5]=f2bf(c.y); r[6]=f2bf(c.z); r[7]=f2bf(c.w);
    *(uint4*)(g_xb + (size_t)(tt * 256 + n) * 1024 + tid * 8) = *(const uint4*)r;
}

// ---------------------------------------------------------------------------
// A fp32 [n][h][l] -> g_Ab bf16 (same layout). grid 256 x 256.
// ---------------------------------------------------------------------------
__global__ __launch_bounds__(256) void cvt_a(const float* __restrict__ A)
{
    int n = blockIdx.x, tid = threadIdx.x;
    int h0 = tid * 4;
    const float* ap = A + (size_t)n * 16384;
    #pragma unroll
    for (int i = 0; i < 4; ++i) {
        const float* row = ap + (size_t)(h0 + i) * 16;
        ushort_t tmp[16];
        #pragma unroll
        for (int l = 0; l < 16; ++l) tmp[l] = f2bf(row[l]);
        ushort_t* dst = g_Ab + (size_t)n * 16384 + (size_t)(h0 + i) * 16;
        *(uint4*)dst       = *(const uint4*)&tmp[0];
        *(uint4*)(dst + 8) = *(const uint4*)&tmp[8];
    }
}

// ---------------------------------------------------------------------------
// Prepack [Wh^T | Wx^T | Wattn^T] -> g_W3 [j][k3] (4096 x 3072).
// grid (48,64) x 256.
// ---------------------------------------------------------------------------
__global__ __launch_bounds__(256) void prepack_w3(
    const float* __restrict__ Wh, const float* __restrict__ Wx,
    const float* __restrict__ Wattn)
{
    __shared__ ushort_t tile[64][66];
    int k0 = blockIdx.x * 64, j0 = blockIdx.y * 64;
    const float* src = (k0 < 1024) ? Wh : (k0 < 2048) ? Wx : Wattn;
    int krel = k0 & 1023;
    int c = threadIdx.x & 63, r4 = threadIdx.x >> 6;
    for (int rr = 0; rr < 64; rr += 4) {
        int r = rr + r4;
        tile[r][c] = f2bf(src[(size_t)(krel + r) * 4096 + j0 + c]);
    }
    __syncthreads();
    for (int rr = 0; rr < 64; rr += 4) {
        int j = rr + r4;
        g_W3[(size_t)(j0 + j) * 3072 + k0 + c] = tile[c][j];
    }
}

// ---------------------------------------------------------------------------
// Init: h0 = c0 = mean over 16 spatial of A. grid 1024 x 256 (gid = (n,h)).
// No logit pass needed -- attn_k(0) computes logits itself from g_Hc[0].
// ---------------------------------------------------------------------------
__global__ __launch_bounds__(256) void init_hc(const float* __restrict__ A)
{
    int gid = blockIdx.x * 256 + threadIdx.x;     // n*1024 + h
    const float* ap = A + ((size_t)gid << 4);
    float4 a0 = *(const float4*)(ap);
    float4 a1 = *(const float4*)(ap + 4);
    float4 a2 = *(const float4*)(ap + 8);
    float4 a3 = *(const float4*)(ap + 12);
    float s = (a0.x+a0.y+a0.z+a0.w) + (a1.x+a1.y+a1.z+a1.w)
            + (a2.x+a2.y+a2.z+a2.w) + (a3.x+a3.y+a3.z+a3.w);
    s *= (1.0f / 16.0f);
    g_Hc[0][gid] = f2bf(s);
    g_c[gid] = s;
}

// ---------------------------------------------------------------------------
// attn_k: one block per n. logits[l] = sum_h h[n,h]*Ab[n,h,l]; softmax;
// attn[n,h] = sum_l w[l]*Ab[n,h,l]. Ab read ONCE into registers (4 rows x 16
// per thread), reused for both passes. Replaces: pw_gemm, hoisted P (32 MB/
// step stream), the gemm's logit epilogue (8 MB/step Ab re-read + atomics),
// and all logit-ring machinery. grid 256 x 256.
// ---------------------------------------------------------------------------
__global__ __launch_bounds__(256) void attn_k(int t)
{
    __shared__ float l1[16 * 257];     // [l][tid] padded
    __shared__ float l2[16 * 16];      // [l][seg]
    __shared__ float wsh[16];
    int n = blockIdx.x, tid = threadIdx.x;

    // h: 4 values per thread
    float hv[4];
    {
        uint2 hraw = *(const uint2*)(g_Hc[t & 1] + n * 1024 + tid * 4);
        const ushort_t* hs = (const ushort_t*)&hraw;
        #pragma unroll
        for (int i = 0; i < 4; ++i) hv[i] = bf2f(hs[i]);
    }
    // Ab rows tid*4 .. tid*4+4 (coalesced 128 B/thread), kept in registers
    float av[4][16];
    const ushort_t* ab = g_Ab + (size_t)n * 16384 + (size_t)tid * 64;
    #pragma unroll
    for (int r = 0; r < 4; ++r) {
        unp8(*(const uint4*)(ab + r * 16), av[r]);
        unp8(*(const uint4*)(ab + r * 16 + 8), av[r] + 8);
    }
    // logit partials over this thread's 4 h
    float lg[16];
    #pragma unroll
    for (int l = 0; l < 16; ++l) {
        float s = 0.f;
        #pragma unroll
        for (int r = 0; r < 4; ++r) s += hv[r] * av[r][l];
        lg[l] = s;
    }
    #pragma unroll
    for (int l = 0; l < 16; ++l) l1[l * 257 + tid] = lg[l];
    __syncthreads();
    {
        int l = tid >> 4, seg = tid & 15;
        float s2 = 0.f;
        #pragma unroll
        for (int i = 0; i < 16; ++i) s2 += l1[l * 257 + seg * 16 + i];
        l2[l * 16 + seg] = s2;
    }
    __syncthreads();
    if (tid < 16) {
        float v = 0.f;
        #pragma unroll
        for (int i = 0; i < 16; ++i) v += l2[tid * 16 + i];
        v *= 0.03125f;                  // 1/sqrt(H)
        float mx = v;
        mx = fmaxf(mx, __shfl_xor(mx, 1));
        mx = fmaxf(mx, __shfl_xor(mx, 2));
        mx = fmaxf(mx, __shfl_xor(mx, 4));
        mx = fmaxf(mx, __shfl_xor(mx, 8));
        float ex = __expf(v - mx);
        float sm = ex;
        sm += __shfl_xor(sm, 1);
        sm += __shfl_xor(sm, 2);
        sm += __shfl_xor(sm, 4);
        sm += __shfl_xor(sm, 8);
        wsh[tid] = ex / sm;
    }
    __syncthreads();
    float w[16];
    #pragma unroll
    for (int l = 0; l < 16; ++l) w[l] = wsh[l];
    ushort_t outp[4];
    #pragma unroll
    for (int r = 0; r < 4; ++r) {
        float a = 0.f;
        #pragma unroll
        for (int l = 0; l < 16; ++l) a += w[l] * av[r][l];
        outp[r] = f2bf(a);
    }
    *(uint2*)(g_attn + (size_t)n * 1024 + tid * 4) = *(const uint2*)outp;
}

// ---------------------------------------------------------------------------
// Per-step GEMM v8 (launched, proven round-4 body): C[256x4096] =
// [h | x_t | attn] @ [Wh;Wx;Wattn] (K=3072, 24 dbuf iters, counted vmcnt(6))
// + bias + LSTM. No P, no logit epilogue -- streams only W3 24 MB + x 0.5 +
// h/attn 1 MB per step (vs round 4's 56 MB). Grid 512 = 8 nt x 64 jt,
// XCD-pinned, 2 blocks/CU (LDS 48 KB).
// ---------------------------------------------------------------------------
__global__ __launch_bounds__(256, 2) void step_gemm(float* __restrict__ out,
                                                    const float* __restrict__ bias, int t)
{
    __shared__ __align__(16) char smem[49152];
    ushort_t* lA0 = (ushort_t*)smem;                 // 32x128 bf16 (8 KB)
    ushort_t* lA1 = (ushort_t*)(smem + 8192);
    ushort_t* lB0 = (ushort_t*)(smem + 16384);       // 64x128 bf16 (16 KB)
    ushort_t* lB1 = (ushort_t*)(smem + 32768);
    float*    lP  = (float*)smem;                    // [4][32*68] epilogue alias (34.8 KB)

    const ushort_t* Hin  = g_Hc[t & 1];
    ushort_t*       Hout = g_Hc[(t + 1) & 1];

    int b = blockIdx.x;
    int xcd = b & 7, r = b >> 3;
    int jt = xcd * 8 + (r & 7), nt = r >> 3;
    int n0 = nt * 32, hh0 = jt * 16;
    int tid = threadIdx.x, lane = tid & 63, wv = tid >> 6;
    int lm = lane & 15, quad = lane >> 4;
    int srow = lane >> 4, sseg = lane & 15;

    const ushort_t* hbase = Hin    + (size_t)(n0 + wv * 8 + srow) * 1024;
    const ushort_t* xbase = g_xb   + ((size_t)t * 256 + n0 + wv * 8 + srow) * 1024;
    const ushort_t* abase = g_attn + (size_t)(n0 + wv * 8 + srow) * 1024;
    const ushort_t* gB0   = g_W3   + (size_t)(wv * 1024 + hh0 + srow) * 3072;

    // ---- prologue: stage tile 0 (h source) ----
    #pragma unroll
    for (int i = 0; i < 2; ++i) {
        int rlow = (wv * 8 + i * 4 + srow) & 15;
        gload16(hbase + (size_t)i * 4 * 1024 + (sseg ^ rlow) * 8, lA0 + (wv * 8 + i * 4) * 128);
    }
    #pragma unroll
    for (int i = 0; i < 4; ++i) {
        int rlow = i * 4 + srow;
        gload16(gB0 + (size_t)i * 4 * 3072 + (sseg ^ rlow) * 8, lB0 + (wv * 16 + i * 4) * 128);
    }

    // ---- K-loop: 24 double-buffered iters over [h|x|attn], vmcnt(6) ----
    floatx4 acc[2][4] = {};
    int segk = wv * 4 + quad;
    for (int it = 0; it < 24; ++it) {
        ushort_t* cA = (it & 1) ? lA1 : lA0;
        ushort_t* cB = (it & 1) ? lB1 : lB0;
        ushort_t* nA = (it & 1) ? lA0 : lA1;
        ushort_t* nB = (it & 1) ? lB0 : lB1;
        if (it < 23) {
            int kk = (it + 1) * 128;
            const ushort_t* aSrc = (kk < 1024) ? (hbase + kk)
                                 : (kk < 2048) ? (xbase + (kk - 1024))
                                               : (abase + (kk - 2048));
            #pragma unroll
            for (int i = 0; i < 2; ++i) {
                int rlow = (wv * 8 + i * 4 + srow) & 15;
                gload16(aSrc + (size_t)i * 4 * 1024 + (sseg ^ rlow) * 8,
                        nA + (wv * 8 + i * 4) * 128);
            }
            #pragma unroll
            for (int i = 0; i < 4; ++i) {
                int rlow = i * 4 + srow;
                gload16(gB0 + (size_t)i * 4 * 3072 + kk + (sseg ^ rlow) * 8,
                        nB + (wv * 16 + i * 4) * 128);
            }
            asm volatile("s_waitcnt vmcnt(6)" ::: "memory");
        } else {
            asm volatile("s_waitcnt vmcnt(0)" ::: "memory");
        }
        __builtin_amdgcn_s_barrier();
        short8 af[2], bq[4];
        #pragma unroll
        for (int i = 0; i < 2; ++i)
            af[i] = *(const short8*)(cA + (i * 16 + lm) * 128 + ((segk ^ lm) * 8));
        #pragma unroll
        for (int j = 0; j < 4; ++j)
            bq[j] = *(const short8*)(cB + (j * 16 + lm) * 128 + ((segk ^ lm) * 8));
        #pragma unroll
        for (int i = 0; i < 2; ++i)
            #pragma unroll
            for (int j = 0; j < 4; ++j)
                acc[i][j] = __builtin_amdgcn_mfma_f32_16x16x32_bf16(af[i], bq[j], acc[i][j], 0, 0, 0);
        asm volatile("s_waitcnt lgkmcnt(0)" ::: "memory");
        __builtin_amdgcn_s_barrier();
    }

    // ---- wave-private partial store ----
    float* my = lP + wv * (32 * 68);
    #pragma unroll
    for (int i = 0; i < 2; ++i)
        #pragma unroll
        for (int j = 0; j < 4; ++j)
            #pragma unroll
            for (int q = 0; q < 4; ++q)
                my[(i * 16 + quad * 4 + q) * 68 + j * 16 + lm] = acc[i][j][q];
    __syncthreads();

    // ---- LSTM pointwise: 4 wave-partials + bias ----
    #pragma unroll
    for (int e = 0; e < 2; ++e) {
        int idx = tid + e * 256;           // (nl, hl)
        int nl = idx >> 4, hl = idx & 15;
        int base = nl * 68 + hl;
        float s0 = lP[base]      + lP[2176 + base]      + lP[4352 + base]      + lP[6528 + base];
        float s1 = lP[base + 16] + lP[2176 + base + 16] + lP[4352 + base + 16] + lP[6528 + base + 16];
        float s2 = lP[base + 32] + lP[2176 + base + 32] + lP[4352 + base + 32] + lP[6528 + base + 32];
        float s3 = lP[base + 48] + lP[2176 + base + 48] + lP[4352 + base + 48] + lP[6528 + base + 48];
        int hg = hh0 + hl;
        float ai  = s0 + bias[hg];
        float afv = s1 + bias[1024 + hg];
        float ao  = s2 + bias[2048 + hg];
        float ag  = s3 + bias[3072 + hg];
        float iv = 1.f / (1.f + __expf(-ai));
        float fv = 1.f / (1.f + __expf(-afv));
        float ov = 1.f / (1.f + __expf(-ao));
        float gv = fast_tanh(ag);
        int ng = n0 + nl;
        float cold = g_c[ng * 1024 + hg];
        float cnew = fv * cold + iv * gv;
        float hnew = ov * fast_tanh(cnew);
        g_c[ng * 1024 + hg] = cnew;
        Hout[ng * 1024 + hg] = f2bf(hnew);
        out[(size_t)ng * (T_SEQ * 1024) + (size_t)t * 1024 + hg] = hnew;
    }
}

// ---------------------------------------------------------------------------
extern "C" void kernel_launch(void* const* d_in, const int* in_sizes, int n_in,
                              void* d_out, int out_size, void* d_ws, size_t ws_size,
                              hipStream_t stream) {
    const float* x     = (const float*)d_in[0];
    const float* A     = (const float*)d_in[1];
    const float* Wx    = (const float*)d_in[2];
    const float* Wh    = (const float*)d_in[3];
    const float* Wattn = (const float*)d_in[4];
    const float* bias  = (const float*)d_in[5];
    float* out = (float*)d_out;

    cvt_x<<<8192, 128, 0, stream>>>(x);
    cvt_a<<<256, 256, 0, stream>>>(A);
    prepack_w3<<<dim3(48, 64), 256, 0, stream>>>(Wh, Wx, Wattn);
    init_hc<<<1024, 256, 0, stream>>>(A);
    for (int t = 0; t < T_SEQ; ++t) {
        attn_k<<<256, 256, 0, stream>>>(t);
        step_gemm<<<512, 256, 0, stream>>>(out, bias, t);
    }
}